// Round 1
// baseline (1253.730 us; speedup 1.0000x reference)
//
#include <hip/hip_runtime.h>
#include <math.h>

#define NPOS 9216   // 96*96

// ---------------------------------------------------------------------------
// Kernel 1: 3x3 conv encoder  inp[3,96,96] -> feat[64,96,96]  (SAME, zero pad)
// ---------------------------------------------------------------------------
__global__ __launch_bounds__(256) void conv_kernel(const float* __restrict__ inp,
                                                   const float* __restrict__ enc_w,
                                                   const float* __restrict__ enc_b,
                                                   float* __restrict__ feat)
{
    int idx = blockIdx.x * 256 + threadIdx.x;      // c*9216 + y*96 + x
    if (idx >= 64 * NPOS) return;
    int c   = idx / NPOS;
    int rem = idx - c * NPOS;
    int y   = rem / 96;
    int x   = rem - y * 96;
    float acc = enc_b[c];
    #pragma unroll
    for (int cin = 0; cin < 3; ++cin) {
        #pragma unroll
        for (int ky = 0; ky < 3; ++ky) {
            int yy = y + ky - 1;
            if (yy < 0 || yy >= 96) continue;
            #pragma unroll
            for (int kx = 0; kx < 3; ++kx) {
                int xx = x + kx - 1;
                if (xx < 0 || xx >= 96) continue;
                acc = fmaf(inp[cin * NPOS + yy * 96 + xx],
                           enc_w[c * 27 + cin * 9 + ky * 3 + kx], acc);
            }
        }
    }
    feat[idx] = acc;
}

// ---------------------------------------------------------------------------
// Kernel 2: A0[pos][o] = sum_{c,t} feat_unfold[c*9+t, pos] * w0[c*9+t][o] + b0[o]
// (3x3 "conv" of feat with w0's first 576 rows, zero-padded like F.unfold)
// One block = 8 consecutive x positions at fixed y; o = threadIdx.x (256 outs).
// ---------------------------------------------------------------------------
__global__ __launch_bounds__(256) void a0_kernel(const float* __restrict__ feat,
                                                 const float* __restrict__ w0,
                                                 const float* __restrict__ b0,
                                                 float* __restrict__ A0)
{
    __shared__ float win[64][3][10];   // [c][dy][dx]: rows y-1..y+1, cols x0-1..x0+8
    const int t   = threadIdx.x;
    const int blk = blockIdx.x;        // y*12 + xchunk
    const int y   = blk / 12;
    const int x0  = (blk - y * 12) * 8;

    for (int i = t; i < 64 * 30; i += 256) {
        int c   = i / 30;
        int rem = i - c * 30;
        int dy  = rem / 10;
        int dx  = rem - dy * 10;
        int gy  = y + dy - 1;
        int gx  = x0 + dx - 1;
        float v = 0.0f;
        if (gy >= 0 && gy < 96 && gx >= 0 && gx < 96)
            v = feat[c * NPOS + gy * 96 + gx];
        win[c][dy][dx] = v;
    }
    __syncthreads();

    float acc[8];
    float bv = b0[t];
    #pragma unroll
    for (int p = 0; p < 8; ++p) acc[p] = bv;

    for (int c = 0; c < 64; ++c) {
        #pragma unroll
        for (int t9 = 0; t9 < 9; ++t9) {
            int ki = t9 / 3;
            int kj = t9 - ki * 3;
            float wv = w0[(c * 9 + t9) * 256 + t];
            #pragma unroll
            for (int p = 0; p < 8; ++p)
                acc[p] = fmaf(win[c][ki][kj + p], wv, acc[p]);
        }
    }
    #pragma unroll
    for (int p = 0; p < 8; ++p)
        A0[(y * 96 + x0 + p) * 256 + t] = acc[p];
}

// ---------------------------------------------------------------------------
// Kernel 3: fused MLP over 64 rows (= 16 queries x 4 ensemble) per block.
// h kept in LDS [64][260] (pad 260 to break final-layer bank conflicts).
// Thread tile: 16 rows (rg = tid>>6, one wave per row-group) x 4 cols (co=tid&63).
// ---------------------------------------------------------------------------
#define FMA4(a, hc, wv)                        \
    a.x = fmaf(hc, wv.x, a.x);                 \
    a.y = fmaf(hc, wv.y, a.y);                 \
    a.z = fmaf(hc, wv.z, a.z);                 \
    a.w = fmaf(hc, wv.w, a.w);

__device__ __forceinline__ void hidden_layer(float (*h)[260],
                                             const float* __restrict__ W,
                                             const float* __restrict__ Bb,
                                             int rg, int co)
{
    float4 acc[16];
    #pragma unroll
    for (int m = 0; m < 16; ++m) acc[m] = make_float4(0.f, 0.f, 0.f, 0.f);

    for (int k4 = 0; k4 < 256; k4 += 4) {
        float4 wv0 = *(const float4*)(W + (k4 + 0) * 256 + co * 4);
        float4 wv1 = *(const float4*)(W + (k4 + 1) * 256 + co * 4);
        float4 wv2 = *(const float4*)(W + (k4 + 2) * 256 + co * 4);
        float4 wv3 = *(const float4*)(W + (k4 + 3) * 256 + co * 4);
        #pragma unroll
        for (int m = 0; m < 16; ++m) {
            float4 hv = *(const float4*)&h[rg * 16 + m][k4];
            FMA4(acc[m], hv.x, wv0);
            FMA4(acc[m], hv.y, wv1);
            FMA4(acc[m], hv.z, wv2);
            FMA4(acc[m], hv.w, wv3);
        }
    }
    __syncthreads();   // all reads of h done before overwrite
    float4 bb = *(const float4*)(Bb + co * 4);
    #pragma unroll
    for (int m = 0; m < 16; ++m) {
        float4 v;
        v.x = fmaxf(acc[m].x + bb.x, 0.0f);
        v.y = fmaxf(acc[m].y + bb.y, 0.0f);
        v.z = fmaxf(acc[m].z + bb.z, 0.0f);
        v.w = fmaxf(acc[m].w + bb.w, 0.0f);
        *(float4*)&h[rg * 16 + m][co * 4] = v;
    }
    __syncthreads();
}

__global__ __launch_bounds__(256) void fused_kernel(
    const float* __restrict__ A0, const float* __restrict__ coord,
    const float* __restrict__ cell, const float* __restrict__ w0,
    const float* __restrict__ w1, const float* __restrict__ b1,
    const float* __restrict__ w2, const float* __restrict__ b2,
    const float* __restrict__ w3, const float* __restrict__ b3,
    const float* __restrict__ w4, const float* __restrict__ b4,
    float* __restrict__ out)
{
    __shared__ float h[64][260];
    __shared__ float pred[64][4];
    __shared__ float s_rel0[64], s_rel1[64], s_rc0[64], s_rc1[64], s_area[64];
    __shared__ int   s_pos[64];

    const int t   = threadIdx.x;
    const int blk = blockIdx.x;

    if (t < 64) {
        int r = blk * 64 + t;
        int q = r >> 2;
        int j = r & 3;                         // (vx,vy): 0:(-,-) 1:(-,+) 2:(+,-) 3:(+,+)
        float vx = (j & 2) ? 1.0f : -1.0f;
        float vy = (j & 1) ? 1.0f : -1.0f;
        float c0 = coord[q * 2 + 0];
        float c1 = coord[q * 2 + 1];
        const float rr  = 1.0f / 96.0f;
        const float bnd = 1.0f - 1e-6f;
        float sc0 = fminf(fmaxf(fmaf(vx, rr, c0) + 1e-6f, -bnd), bnd);
        float sc1 = fminf(fmaxf(fmaf(vy, rr, c1) + 1e-6f, -bnd), bnd);
        float fy = (sc0 + 1.0f) * 48.0f - 0.5f;
        float fx = (sc1 + 1.0f) * 48.0f - 0.5f;
        int iy = (int)rintf(fy); iy = iy < 0 ? 0 : (iy > 95 ? 95 : iy);
        int ix = (int)rintf(fx); ix = ix < 0 ? 0 : (ix > 95 ? 95 : ix);
        float fcy = -1.0f + (2.0f * (float)iy + 1.0f) / 96.0f;
        float fcx = -1.0f + (2.0f * (float)ix + 1.0f) / 96.0f;
        float rel0 = (c0 - fcy) * 96.0f;
        float rel1 = (c1 - fcx) * 96.0f;
        s_pos[t]  = iy * 96 + ix;
        s_rel0[t] = rel0;
        s_rel1[t] = rel1;
        s_rc0[t]  = cell[q * 2 + 0] * 96.0f;
        s_rc1[t]  = cell[q * 2 + 1] * 96.0f;
        s_area[t] = fabsf(rel0 * rel1) + 1e-9f;
    }
    __syncthreads();

    // ---- layer 0: h = relu(A0[pos] + rel0*w0[576] + rel1*w0[577] + rc*w0[578..579])
    {
        float wa = w0[576 * 256 + t];
        float wb = w0[577 * 256 + t];
        float wc = w0[578 * 256 + t];
        float wd = w0[579 * 256 + t];
        #pragma unroll 4
        for (int m = 0; m < 64; ++m) {
            float v = A0[s_pos[m] * 256 + t];
            v = fmaf(s_rel0[m], wa, v);
            v = fmaf(s_rel1[m], wb, v);
            v = fmaf(s_rc0[m], wc, v);
            v = fmaf(s_rc1[m], wd, v);
            h[m][t] = fmaxf(v, 0.0f);
        }
    }
    __syncthreads();

    const int rg = t >> 6;
    const int co = t & 63;
    hidden_layer(h, w1, b1, rg, co);
    hidden_layer(h, w2, b2, rg, co);
    hidden_layer(h, w3, b3, rg, co);

    // ---- final layer 256 -> 3
    {
        int m  = t >> 2;
        int oo = t & 3;
        float s = 0.0f;
        if (oo < 3) {
            s = b4[oo];
            for (int k = 0; k < 256; ++k)
                s = fmaf(h[m][k], w4[k * 3 + oo], s);
        }
        pred[m][oo] = s;
    }
    __syncthreads();

    // ---- local-ensemble combine (diagonal area swap), 16 queries per block
    if (t < 48) {
        int ql = t / 3;
        int o  = t - ql * 3;
        int mb = ql * 4;
        float a0 = s_area[mb + 0];
        float a1 = s_area[mb + 1];
        float a2 = s_area[mb + 2];
        float a3 = s_area[mb + 3];
        float tot = a0 + a1 + a2 + a3;
        float rv = pred[mb + 0][o] * a3 + pred[mb + 1][o] * a2 +
                   pred[mb + 2][o] * a1 + pred[mb + 3][o] * a0;
        out[(blk * 16 + ql) * 3 + o] = rv / tot;
    }
}

// ---------------------------------------------------------------------------
extern "C" void kernel_launch(void* const* d_in, const int* in_sizes, int n_in,
                              void* d_out, int out_size, void* d_ws, size_t ws_size,
                              hipStream_t stream)
{
    (void)in_sizes; (void)n_in; (void)out_size; (void)ws_size;
    const float* inp   = (const float*)d_in[0];
    const float* coord = (const float*)d_in[1];
    const float* cell  = (const float*)d_in[2];
    const float* enc_w = (const float*)d_in[3];
    const float* enc_b = (const float*)d_in[4];
    const float* w0 = (const float*)d_in[5];
    const float* b0 = (const float*)d_in[6];
    const float* w1 = (const float*)d_in[7];
    const float* b1 = (const float*)d_in[8];
    const float* w2 = (const float*)d_in[9];
    const float* b2 = (const float*)d_in[10];
    const float* w3 = (const float*)d_in[11];
    const float* b3 = (const float*)d_in[12];
    const float* w4 = (const float*)d_in[13];
    const float* b4 = (const float*)d_in[14];
    float* outp = (float*)d_out;

    float* feat = (float*)d_ws;            // 64*9216 floats  (2.36 MB)
    float* A0   = feat + 64 * NPOS;        // 9216*256 floats (9.44 MB)

    conv_kernel<<<dim3((64 * NPOS + 255) / 256), dim3(256), 0, stream>>>(inp, enc_w, enc_b, feat);
    a0_kernel<<<dim3(96 * 12), dim3(256), 0, stream>>>(feat, w0, b0, A0);
    fused_kernel<<<dim3(4096), dim3(256), 0, stream>>>(A0, coord, cell, w0,
                                                       w1, b1, w2, b2, w3, b3, w4, b4,
                                                       outp);
}

// Round 2
// 279.650 us; speedup vs baseline: 4.4832x; 4.4832x over previous
//
#include <hip/hip_runtime.h>
#include <math.h>

#define NPOS 9216   // 96*96

using half8 = __attribute__((ext_vector_type(8))) _Float16;
using f32x4 = __attribute__((ext_vector_type(4))) float;

// ---------------------------------------------------------------------------
// Kernel 1: 3x3 conv encoder  inp[3,96,96] -> feat[64,96,96]  (SAME, zero pad)
// ---------------------------------------------------------------------------
__global__ __launch_bounds__(256) void conv_kernel(const float* __restrict__ inp,
                                                   const float* __restrict__ enc_w,
                                                   const float* __restrict__ enc_b,
                                                   float* __restrict__ feat)
{
    int idx = blockIdx.x * 256 + threadIdx.x;      // c*9216 + y*96 + x
    if (idx >= 64 * NPOS) return;
    int c   = idx / NPOS;
    int rem = idx - c * NPOS;
    int y   = rem / 96;
    int x   = rem - y * 96;
    float acc = enc_b[c];
    #pragma unroll
    for (int cin = 0; cin < 3; ++cin) {
        #pragma unroll
        for (int ky = 0; ky < 3; ++ky) {
            int yy = y + ky - 1;
            if (yy < 0 || yy >= 96) continue;
            #pragma unroll
            for (int kx = 0; kx < 3; ++kx) {
                int xx = x + kx - 1;
                if (xx < 0 || xx >= 96) continue;
                acc = fmaf(inp[cin * NPOS + yy * 96 + xx],
                           enc_w[c * 27 + cin * 9 + ky * 3 + kx], acc);
            }
        }
    }
    feat[idx] = acc;
}

// ---------------------------------------------------------------------------
// Kernel 2: A0[pos][o] = sum_{c,t} feat_unfold[c*9+t, pos] * w0[c*9+t][o] + b0[o]
// ---------------------------------------------------------------------------
__global__ __launch_bounds__(256) void a0_kernel(const float* __restrict__ feat,
                                                 const float* __restrict__ w0,
                                                 const float* __restrict__ b0,
                                                 float* __restrict__ A0)
{
    __shared__ float win[64][3][10];   // [c][dy][dx]
    const int t   = threadIdx.x;
    const int blk = blockIdx.x;        // y*12 + xchunk
    const int y   = blk / 12;
    const int x0  = (blk - y * 12) * 8;

    for (int i = t; i < 64 * 30; i += 256) {
        int c   = i / 30;
        int rem = i - c * 30;
        int dy  = rem / 10;
        int dx  = rem - dy * 10;
        int gy  = y + dy - 1;
        int gx  = x0 + dx - 1;
        float v = 0.0f;
        if (gy >= 0 && gy < 96 && gx >= 0 && gx < 96)
            v = feat[c * NPOS + gy * 96 + gx];
        win[c][dy][dx] = v;
    }
    __syncthreads();

    float acc[8];
    float bv = b0[t];
    #pragma unroll
    for (int p = 0; p < 8; ++p) acc[p] = bv;

    for (int c = 0; c < 64; ++c) {
        #pragma unroll
        for (int t9 = 0; t9 < 9; ++t9) {
            int ki = t9 / 3;
            int kj = t9 - ki * 3;
            float wv = w0[(c * 9 + t9) * 256 + t];
            #pragma unroll
            for (int p = 0; p < 8; ++p)
                acc[p] = fmaf(win[c][ki][kj + p], wv, acc[p]);
        }
    }
    #pragma unroll
    for (int p = 0; p < 8; ++p)
        A0[(y * 96 + x0 + p) * 256 + t] = acc[p];
}

// ---------------------------------------------------------------------------
// Kernel 3: pack w1/w2/w3 (256x256) and w4 (256x3, padded to 16 cols) into
// fragment-ordered f16 for mfma_f32_16x16x32_f16:
//   wf[ l*65536 + ((ks*16 + ntB)*64 + lane)*8 + j ] = W[k][n]
//   with n = ntB*16 + (lane&15), k = ks*32 + (lane>>4)*8 + j
// ---------------------------------------------------------------------------
__global__ __launch_bounds__(256) void pack_w(const float* __restrict__ w1,
                                              const float* __restrict__ w2,
                                              const float* __restrict__ w3,
                                              const float* __restrict__ w4,
                                              _Float16* __restrict__ wf)
{
    int idx = blockIdx.x * 256 + threadIdx.x;
    if (idx < 3 * 65536) {
        int l = idx >> 16;
        int r = idx & 65535;
        int j    = r & 7;
        int lane = (r >> 3) & 63;
        int ntB  = (r >> 9) & 15;
        int ks   = r >> 13;
        int n = ntB * 16 + (lane & 15);
        int k = ks * 32 + (lane >> 4) * 8 + j;
        const float* W = (l == 0) ? w1 : (l == 1) ? w2 : w3;
        wf[idx] = (_Float16)W[k * 256 + n];
    } else if (idx < 3 * 65536 + 4096) {
        int r = idx - 3 * 65536;
        int j    = r & 7;
        int lane = (r >> 3) & 63;
        int ks   = r >> 9;
        int n = lane & 15;
        int k = ks * 32 + (lane >> 4) * 8 + j;
        wf[idx] = (n < 3) ? (_Float16)w4[k * 3 + n] : (_Float16)0.0f;
    }
}

// ---------------------------------------------------------------------------
// Kernel 4: fused MLP, 128 rows (= 32 queries x 4 ensemble) per block.
// 8 waves: wave (wm,wn) computes rows [wm*64..) x cols [wn*64..) via MFMA.
// h in LDS as f16 [128][264] (528B stride -> bank rotation, ~2-way only).
// ---------------------------------------------------------------------------
__device__ __forceinline__ void hidden_mfma(_Float16 (*h)[264],
                                            const _Float16* __restrict__ W,
                                            const float* __restrict__ bias,
                                            int wm, int wn, int lane)
{
    const int l15 = lane & 15;
    const int l4  = lane >> 4;
    f32x4 acc[4][4];
    #pragma unroll
    for (int mt = 0; mt < 4; ++mt)
        #pragma unroll
        for (int nt = 0; nt < 4; ++nt)
            acc[mt][nt] = (f32x4){0.f, 0.f, 0.f, 0.f};

    #pragma unroll
    for (int ks = 0; ks < 8; ++ks) {
        half8 a[4], b[4];
        #pragma unroll
        for (int mt = 0; mt < 4; ++mt)
            a[mt] = *(const half8*)&h[wm * 64 + mt * 16 + l15][ks * 32 + l4 * 8];
        #pragma unroll
        for (int nt = 0; nt < 4; ++nt)
            b[nt] = *(const half8*)&W[((ks * 16 + wn * 4 + nt) * 64 + lane) * 8];
        #pragma unroll
        for (int mt = 0; mt < 4; ++mt)
            #pragma unroll
            for (int nt = 0; nt < 4; ++nt)
                acc[mt][nt] = __builtin_amdgcn_mfma_f32_16x16x32_f16(a[mt], b[nt], acc[mt][nt], 0, 0, 0);
    }
    __syncthreads();   // all reads of h done before overwrite
    #pragma unroll
    for (int nt = 0; nt < 4; ++nt) {
        int col = wn * 64 + nt * 16 + l15;
        float bv = bias[col];
        #pragma unroll
        for (int mt = 0; mt < 4; ++mt) {
            int rowb = wm * 64 + mt * 16 + l4 * 4;
            #pragma unroll
            for (int i = 0; i < 4; ++i)
                h[rowb + i][col] = (_Float16)fmaxf(acc[mt][nt][i] + bv, 0.0f);
        }
    }
    __syncthreads();
}

__global__ __launch_bounds__(512, 4) void fused_kernel(
    const float* __restrict__ A0, const float* __restrict__ coord,
    const float* __restrict__ cell, const float* __restrict__ w0,
    const float* __restrict__ b1, const float* __restrict__ b2,
    const float* __restrict__ b3, const float* __restrict__ b4,
    const _Float16* __restrict__ wf,
    float* __restrict__ out)
{
    __shared__ _Float16 h[128][264];
    __shared__ float pred[128][4];
    __shared__ float s_rel0[128], s_rel1[128], s_rc0[128], s_rc1[128], s_area[128];
    __shared__ int   s_pos[128];

    const int t   = threadIdx.x;
    const int blk = blockIdx.x;

    if (t < 128) {
        int r = blk * 128 + t;
        int q = r >> 2;
        int j = r & 3;                         // (vx,vy): 0:(-,-) 1:(-,+) 2:(+,-) 3:(+,+)
        float vx = (j & 2) ? 1.0f : -1.0f;
        float vy = (j & 1) ? 1.0f : -1.0f;
        float c0 = coord[q * 2 + 0];
        float c1 = coord[q * 2 + 1];
        const float rr  = 1.0f / 96.0f;
        const float bnd = 1.0f - 1e-6f;
        float sc0 = fminf(fmaxf(fmaf(vx, rr, c0) + 1e-6f, -bnd), bnd);
        float sc1 = fminf(fmaxf(fmaf(vy, rr, c1) + 1e-6f, -bnd), bnd);
        float fy = (sc0 + 1.0f) * 48.0f - 0.5f;
        float fx = (sc1 + 1.0f) * 48.0f - 0.5f;
        int iy = (int)rintf(fy); iy = iy < 0 ? 0 : (iy > 95 ? 95 : iy);
        int ix = (int)rintf(fx); ix = ix < 0 ? 0 : (ix > 95 ? 95 : ix);
        float fcy = -1.0f + (2.0f * (float)iy + 1.0f) / 96.0f;
        float fcx = -1.0f + (2.0f * (float)ix + 1.0f) / 96.0f;
        float rel0 = (c0 - fcy) * 96.0f;
        float rel1 = (c1 - fcx) * 96.0f;
        s_pos[t]  = iy * 96 + ix;
        s_rel0[t] = rel0;
        s_rel1[t] = rel1;
        s_rc0[t]  = cell[q * 2 + 0] * 96.0f;
        s_rc1[t]  = cell[q * 2 + 1] * 96.0f;
        s_area[t] = fabsf(rel0 * rel1) + 1e-9f;
    }
    __syncthreads();

    // ---- layer 0: h = relu(A0[pos] + rel0*w0[576] + rel1*w0[577] + rc*w0[578..579])
    {
        int col = t & 255;
        int m0  = (t >> 8) * 64;
        float wa = w0[576 * 256 + col];
        float wb = w0[577 * 256 + col];
        float wc = w0[578 * 256 + col];
        float wd = w0[579 * 256 + col];
        #pragma unroll 4
        for (int mm = 0; mm < 64; ++mm) {
            int m = m0 + mm;
            float v = A0[s_pos[m] * 256 + col];
            v = fmaf(s_rel0[m], wa, v);
            v = fmaf(s_rel1[m], wb, v);
            v = fmaf(s_rc0[m], wc, v);
            v = fmaf(s_rc1[m], wd, v);
            h[m][col] = (_Float16)fmaxf(v, 0.0f);
        }
    }
    __syncthreads();

    const int wave = t >> 6;
    const int lane = t & 63;
    const int wm = wave >> 2;
    const int wn = wave & 3;

    hidden_mfma(h, wf,             b1, wm, wn, lane);
    hidden_mfma(h, wf + 65536,     b2, wm, wn, lane);
    hidden_mfma(h, wf + 2 * 65536, b3, wm, wn, lane);

    // ---- final layer 256 -> 3 via MFMA (w4 padded to 16 cols); wave = m-tile
    {
        const int l15 = lane & 15;
        const int l4  = lane >> 4;
        const _Float16* W4 = wf + 3 * 65536;
        f32x4 acc = (f32x4){0.f, 0.f, 0.f, 0.f};
        #pragma unroll
        for (int ks = 0; ks < 8; ++ks) {
            half8 a = *(const half8*)&h[wave * 16 + l15][ks * 32 + l4 * 8];
            half8 b = *(const half8*)&W4[(ks * 64 + lane) * 8];
            acc = __builtin_amdgcn_mfma_f32_16x16x32_f16(a, b, acc, 0, 0, 0);
        }
        if (l15 < 3) {
            float bv = b4[l15];
            #pragma unroll
            for (int i = 0; i < 4; ++i)
                pred[wave * 16 + l4 * 4 + i][l15] = acc[i] + bv;
        }
    }
    __syncthreads();

    // ---- local-ensemble combine (diagonal area swap), 32 queries per block
    if (t < 96) {
        int ql = t / 3;
        int o  = t - ql * 3;
        int mb = ql * 4;
        float a0 = s_area[mb + 0];
        float a1 = s_area[mb + 1];
        float a2 = s_area[mb + 2];
        float a3 = s_area[mb + 3];
        float tot = a0 + a1 + a2 + a3;
        float rv = pred[mb + 0][o] * a3 + pred[mb + 1][o] * a2 +
                   pred[mb + 2][o] * a1 + pred[mb + 3][o] * a0;
        out[(blk * 32 + ql) * 3 + o] = rv / tot;
    }
}

// ---------------------------------------------------------------------------
extern "C" void kernel_launch(void* const* d_in, const int* in_sizes, int n_in,
                              void* d_out, int out_size, void* d_ws, size_t ws_size,
                              hipStream_t stream)
{
    (void)in_sizes; (void)n_in; (void)out_size; (void)ws_size;
    const float* inp   = (const float*)d_in[0];
    const float* coord = (const float*)d_in[1];
    const float* cell  = (const float*)d_in[2];
    const float* enc_w = (const float*)d_in[3];
    const float* enc_b = (const float*)d_in[4];
    const float* w0 = (const float*)d_in[5];
    const float* b0 = (const float*)d_in[6];
    const float* w1 = (const float*)d_in[7];
    const float* b1 = (const float*)d_in[8];
    const float* w2 = (const float*)d_in[9];
    const float* b2 = (const float*)d_in[10];
    const float* w3 = (const float*)d_in[11];
    const float* b3 = (const float*)d_in[12];
    const float* w4 = (const float*)d_in[13];
    const float* b4 = (const float*)d_in[14];
    float* outp = (float*)d_out;

    float*    feat = (float*)d_ws;                 // 64*9216 floats  (2.36 MB)
    float*    A0   = feat + 64 * NPOS;             // 9216*256 floats (9.44 MB)
    _Float16* wf   = (_Float16*)(A0 + NPOS * 256); // 200704 halfs    (0.40 MB)

    conv_kernel<<<dim3((64 * NPOS + 255) / 256), dim3(256), 0, stream>>>(inp, enc_w, enc_b, feat);
    a0_kernel<<<dim3(96 * 12), dim3(256), 0, stream>>>(feat, w0, b0, A0);
    pack_w<<<dim3((3 * 65536 + 4096 + 255) / 256), dim3(256), 0, stream>>>(w1, w2, w3, w4, wf);
    fused_kernel<<<dim3(2048), dim3(512), 0, stream>>>(A0, coord, cell, w0,
                                                       b1, b2, b3, b4, wf, outp);
}